// Round 2
// baseline (95.264 us; speedup 1.0000x reference)
//
#include <hip/hip_runtime.h>
#include <math.h>

// Problem constants (reference: B=2048, CI=32, CO=32, A=16, ITER_NUM=5)
constexpr int CI = 32;
constexpr int CO = 32;
constexpr int A  = 16;
constexpr int Bb = 2048;
constexpr float INV_N   = 1.0f / 65536.0f;
constexpr float INV_NM1 = 1.0f / 65535.0f;

// d_ws float layout
constexpr int WS_SUMS  = 0;               // [CI][A]      = 512 floats
constexpr int WS_PRODS = 512;             // [CI][A][A]   = 8192 floats
constexpr int WS_W     = 512 + 8192;      // [CI][A][A]   = 8192 floats
constexpr int WS_ZERO_BYTES = (512 + 8192) * 4;  // sums+prods must start at 0

// ---------------------------------------------------------------------------
// Kernel 1: per-capsule raw sums S[a] = sum x_a, P[a][b] = sum x_a x_b.
// Grid: 32 ci * 32 chunks = 1024 blocks of 256 threads.
// A quad of lanes owns one 16-float vector; lane (tid&3) accumulates rows
// a0 = (tid&3)*4 .. a0+3 against all 16 columns (4x16 slab, 64 regs).
// ---------------------------------------------------------------------------
__global__ __launch_bounds__(256) void k_stats(const float* __restrict__ x,
                                               float* __restrict__ ws) {
    const int ci    = blockIdx.x & 31;
    const int chunk = blockIdx.x >> 5;          // 0..31
    const int tid   = threadIdx.x;
    const int sub   = tid & 3;                  // row-group selector
    const int quad  = tid >> 2;                 // 0..63 vector slot in block

    float acc[4][16];
    float sacc[4];
#pragma unroll
    for (int i = 0; i < 4; ++i) {
        sacc[i] = 0.0f;
#pragma unroll
        for (int b2 = 0; b2 < 16; ++b2) acc[i][b2] = 0.0f;
    }

    const int n_base = chunk * 2048;            // 2048 vectors per block
    for (int it = 0; it < 32; ++it) {           // 32 iters * 64 vectors
        const int n  = n_base + it * 64 + quad;
        const int b  = n >> 5;                  // batch index
        const int co = n & 31;
        const float* vptr = x + ((size_t)(b * CI + ci) * CO + co) * A;

        float v[16];
#pragma unroll
        for (int j = 0; j < 4; ++j) {           // compile-time dest indices
            const float4 f = *reinterpret_cast<const float4*>(vptr + j * 4);
            v[4 * j + 0] = f.x; v[4 * j + 1] = f.y;
            v[4 * j + 2] = f.z; v[4 * j + 3] = f.w;
        }
        // this lane's 4 rows: chunk `sub` of the same vector (L1 hit)
        const float4 fa = *reinterpret_cast<const float4*>(vptr + sub * 4);
        const float va[4] = {fa.x, fa.y, fa.z, fa.w};

#pragma unroll
        for (int i = 0; i < 4; ++i) {
            sacc[i] += va[i];
#pragma unroll
            for (int b2 = 0; b2 < 16; ++b2) acc[i][b2] += va[i] * v[b2];
        }
    }

    // Butterfly-reduce across the 16 quads of the wave (lanes with same sub).
#pragma unroll
    for (int m = 4; m < 64; m <<= 1) {
#pragma unroll
        for (int i = 0; i < 4; ++i) {
            sacc[i] += __shfl_xor(sacc[i], m, 64);
#pragma unroll
            for (int b2 = 0; b2 < 16; ++b2)
                acc[i][b2] += __shfl_xor(acc[i][b2], m, 64);
        }
    }

    // Cross-wave reduce in LDS: lanes 0..3 of each wave hold wave totals.
    __shared__ float red[4][272];
    const int wv = tid >> 6;
    if ((tid & 63) < 4) {
#pragma unroll
        for (int i = 0; i < 4; ++i) {
#pragma unroll
            for (int b2 = 0; b2 < 16; ++b2)
                red[wv][sub * 68 + i * 16 + b2] = acc[i][b2];
            red[wv][sub * 68 + 64 + i] = sacc[i];
        }
    }
    __syncthreads();
    // 272 reduction slots, 256 threads: strided loop (BUGFIX: tid<272 missed
    // slots 256..271 -> S[12..15] and P[15][4..15] were never accumulated).
    for (int e = tid; e < 272; e += 256) {
        const float s = red[0][e] + red[1][e] + red[2][e] + red[3][e];
        const int sub2 = e / 68;
        const int k    = e - sub2 * 68;
        if (k < 64) {
            const int row = sub2 * 4 + (k >> 4);
            const int col = k & 15;
            atomicAdd(&ws[WS_PRODS + ci * 256 + row * 16 + col], s);
        } else {
            const int row = sub2 * 4 + (k - 64);
            atomicAdd(&ws[WS_SUMS + ci * 16 + row], s);
        }
    }
}

// ---------------------------------------------------------------------------
// Kernel 2: Newton-Schulz inverse sqrt of the 16x16 covariance, per capsule.
// 32 blocks (one per ci) of 256 threads (one per matrix element).
// ---------------------------------------------------------------------------
__global__ __launch_bounds__(256) void k_ns(float* __restrict__ ws) {
    const int ci  = blockIdx.x;
    const int tid = threadIdx.x;
    const int r = tid >> 4, c = tid & 15;

    __shared__ float sig[16][17];
    __shared__ float p[16][17];
    __shared__ float t1[16][17];
    __shared__ float t2[16][17];
    __shared__ float trace_s;

    const float* P = ws + WS_PRODS + ci * 256;
    const float* S = ws + WS_SUMS + ci * 16;

    const float Sr = S[r], Sc = S[c];
    sig[r][c] = (P[r * 16 + c] - Sr * Sc * INV_N) * INV_NM1;
    __syncthreads();

    if (tid == 0) {
        float tr = 0.0f;
        for (int i = 0; i < 16; ++i) tr += sig[i][i];
        trace_s = tr;
    }
    __syncthreads();
    const float tr = trace_s;

    sig[r][c] = sig[r][c] / tr;                 // sigma_n
    p[r][c]   = (r == c) ? 1.0f : 0.0f;
    __syncthreads();

    for (int it = 0; it < 5; ++it) {
        float a = 0.0f;
        for (int k = 0; k < 16; ++k) a += p[r][k] * p[k][c];
        t1[r][c] = a;
        __syncthreads();
        float b2 = 0.0f;
        for (int k = 0; k < 16; ++k) b2 += t1[r][k] * p[k][c];
        t2[r][c] = b2;
        __syncthreads();
        float d = 0.0f;
        for (int k = 0; k < 16; ++k) d += t2[r][k] * sig[k][c];
        const float np = 0.5f * (3.0f * p[r][c] - d);
        __syncthreads();                        // all reads of p done
        p[r][c] = np;
        __syncthreads();
    }

    ws[WS_W + ci * 256 + r * 16 + c] = p[r][c] / sqrtf(tr);
}

// ---------------------------------------------------------------------------
// Kernel 3: out = ((x - m) @ W) * gamma + beta, folded as x @ (W*g) + c0.
// Grid: 32 ci * 64 chunks = 2048 blocks of 256 threads; quad owns a vector,
// lane (tid&3) produces output columns b0..b0+3 (W slab kept in registers).
// ---------------------------------------------------------------------------
__global__ __launch_bounds__(256) void k_apply(const float* __restrict__ x,
                                               const float* __restrict__ gamma,
                                               const float* __restrict__ beta,
                                               const float* __restrict__ ws,
                                               float* __restrict__ out) {
    const int ci    = blockIdx.x & 31;
    const int chunk = blockIdx.x >> 5;          // 0..63
    const int tid   = threadIdx.x;
    const int sub   = tid & 3;
    const int quad  = tid >> 2;
    const int b0    = sub * 4;

    const float* W = ws + WS_W + ci * 256;
    const float* S = ws + WS_SUMS + ci * 16;

    float g[4], c0[4];
#pragma unroll
    for (int i = 0; i < 4; ++i) g[i] = gamma[ci * 16 + b0 + i];

    float wg[16][4];
    float bias[4] = {0.0f, 0.0f, 0.0f, 0.0f};
#pragma unroll
    for (int a = 0; a < 16; ++a) {
        const float4 wr = *reinterpret_cast<const float4*>(W + a * 16 + b0);
        const float m = S[a] * INV_N;
        wg[a][0] = wr.x * g[0]; wg[a][1] = wr.y * g[1];
        wg[a][2] = wr.z * g[2]; wg[a][3] = wr.w * g[3];
        bias[0] += m * wr.x; bias[1] += m * wr.y;
        bias[2] += m * wr.z; bias[3] += m * wr.w;
    }
#pragma unroll
    for (int i = 0; i < 4; ++i)
        c0[i] = beta[ci * 16 + b0 + i] - bias[i] * g[i];

    const int n_base = chunk * 1024;            // 1024 vectors per block
    for (int it = 0; it < 16; ++it) {
        const int n  = n_base + it * 64 + quad;
        const int b  = n >> 5;
        const int co = n & 31;
        const size_t voff = ((size_t)(b * CI + ci) * CO + co) * A;
        const float* vptr = x + voff;

        float v[16];
#pragma unroll
        for (int j = 0; j < 4; ++j) {
            const float4 f = *reinterpret_cast<const float4*>(vptr + j * 4);
            v[4 * j + 0] = f.x; v[4 * j + 1] = f.y;
            v[4 * j + 2] = f.z; v[4 * j + 3] = f.w;
        }

        float acc[4] = {c0[0], c0[1], c0[2], c0[3]};
#pragma unroll
        for (int a = 0; a < 16; ++a) {
#pragma unroll
            for (int i = 0; i < 4; ++i) acc[i] += v[a] * wg[a][i];
        }

        float4 o;
        o.x = acc[0]; o.y = acc[1]; o.z = acc[2]; o.w = acc[3];
        *reinterpret_cast<float4*>(out + voff + b0) = o;
    }
}

// ---------------------------------------------------------------------------
extern "C" void kernel_launch(void* const* d_in, const int* in_sizes, int n_in,
                              void* d_out, int out_size, void* d_ws, size_t ws_size,
                              hipStream_t stream) {
    const float* x     = (const float*)d_in[0];
    const float* gamma = (const float*)d_in[1];
    const float* beta  = (const float*)d_in[2];
    float* out = (float*)d_out;
    float* ws  = (float*)d_ws;

    hipMemsetAsync(d_ws, 0, WS_ZERO_BYTES, stream);
    k_stats<<<dim3(1024), dim3(256), 0, stream>>>(x, ws);
    k_ns<<<dim3(32), dim3(256), 0, stream>>>(ws);
    k_apply<<<dim3(2048), dim3(256), 0, stream>>>(x, gamma, beta, ws, out);
}

// Round 3
// 90.690 us; speedup vs baseline: 1.0504x; 1.0504x over previous
//
#include <hip/hip_runtime.h>
#include <math.h>

// Problem constants (reference: B=2048, CI=32, CO=32, A=16, ITER_NUM=5)
constexpr int CI = 32;
constexpr int CO = 32;
constexpr int A  = 16;
constexpr float INV_N   = 1.0f / 65536.0f;
constexpr float INV_NM1 = 1.0f / 65535.0f;

constexpr int NCHUNK = 32;                 // stats chunks per capsule
constexpr int PART_STRIDE = 272;           // 4 subs * 68 (64 prods + 4 sums)

// d_ws float layout (no zero-init required anywhere):
//   WS_PART: [CI][NCHUNK][272] per-block partial sums (private slots)
//   WS_W:    [CI][256] whitening matrices
constexpr int WS_PART = 0;
constexpr int WS_W    = CI * NCHUNK * PART_STRIDE;   // 278528

// ---------------------------------------------------------------------------
// Kernel 1: per-capsule raw sums S[a] = sum x_a, P[a][b] = sum x_a x_b.
// Grid: 32 ci * 32 chunks = 1024 blocks of 256 threads.
// A quad of lanes owns one 16-float vector; lane (tid&3) accumulates rows
// a0 = (tid&3)*4 .. a0+3 against all 16 columns (4x16 slab in registers).
// Block total goes to a PRIVATE ws slot -> no memset, no atomics.
// ---------------------------------------------------------------------------
__global__ __launch_bounds__(256) void k_stats(const float* __restrict__ x,
                                               float* __restrict__ ws) {
    const int ci    = blockIdx.x & 31;
    const int chunk = blockIdx.x >> 5;          // 0..31
    const int tid   = threadIdx.x;
    const int sub   = tid & 3;                  // row-group selector
    const int quad  = tid >> 2;                 // 0..63 vector slot in block

    float acc[4][16];
    float sacc[4];
#pragma unroll
    for (int i = 0; i < 4; ++i) {
        sacc[i] = 0.0f;
#pragma unroll
        for (int b2 = 0; b2 < 16; ++b2) acc[i][b2] = 0.0f;
    }

    const int n_base = chunk * 2048;            // 2048 vectors per block
    for (int it = 0; it < 32; ++it) {           // 32 iters * 64 vectors
        const int n  = n_base + it * 64 + quad;
        const int b  = n >> 5;                  // batch index
        const int co = n & 31;
        const float* vptr = x + ((size_t)(b * CI + ci) * CO + co) * A;

        float v[16];
#pragma unroll
        for (int j = 0; j < 4; ++j) {           // compile-time dest indices
            const float4 f = *reinterpret_cast<const float4*>(vptr + j * 4);
            v[4 * j + 0] = f.x; v[4 * j + 1] = f.y;
            v[4 * j + 2] = f.z; v[4 * j + 3] = f.w;
        }
        // this lane's 4 rows: chunk `sub` of the same vector (L1 hit)
        const float4 fa = *reinterpret_cast<const float4*>(vptr + sub * 4);
        const float va[4] = {fa.x, fa.y, fa.z, fa.w};

#pragma unroll
        for (int i = 0; i < 4; ++i) {
            sacc[i] += va[i];
#pragma unroll
            for (int b2 = 0; b2 < 16; ++b2) acc[i][b2] += va[i] * v[b2];
        }
    }

    // Butterfly-reduce across the 16 quads of the wave (lanes with same sub).
#pragma unroll
    for (int m = 4; m < 64; m <<= 1) {
#pragma unroll
        for (int i = 0; i < 4; ++i) {
            sacc[i] += __shfl_xor(sacc[i], m, 64);
#pragma unroll
            for (int b2 = 0; b2 < 16; ++b2)
                acc[i][b2] += __shfl_xor(acc[i][b2], m, 64);
        }
    }

    // Cross-wave reduce in LDS: lanes 0..3 of each wave hold wave totals.
    __shared__ float red[4][272];
    const int wv = tid >> 6;
    if ((tid & 63) < 4) {
#pragma unroll
        for (int i = 0; i < 4; ++i) {
#pragma unroll
            for (int b2 = 0; b2 < 16; ++b2)
                red[wv][sub * 68 + i * 16 + b2] = acc[i][b2];
            red[wv][sub * 68 + 64 + i] = sacc[i];
        }
    }
    __syncthreads();
    // 272 slots over 256 threads: strided loop; PRIVATE slot, plain store.
    float* slot = ws + WS_PART + (ci * NCHUNK + chunk) * PART_STRIDE;
    for (int e = tid; e < 272; e += 256) {
        slot[e] = red[0][e] + red[1][e] + red[2][e] + red[3][e];
    }
}

// ---------------------------------------------------------------------------
// Kernel 2: reduce chunk partials, then Newton-Schulz inverse sqrt of the
// 16x16 covariance. 32 blocks (one per ci) of 256 threads.
// Partial layout per slot: e = sub*68 + k; k<64 -> P[sub*4+(k>>4)][k&15],
//                          k>=64 -> S[sub*4+(k-64)].
// ---------------------------------------------------------------------------
__global__ __launch_bounds__(256) void k_ns(float* __restrict__ ws) {
    const int ci  = blockIdx.x;
    const int tid = threadIdx.x;
    const int r = tid >> 4, c = tid & 15;

    __shared__ float red2[272];
    __shared__ float sig[16][17];
    __shared__ float p[16][17];
    __shared__ float t1[16][17];
    __shared__ float t2[16][17];
    __shared__ float trace_s;

    // Reduce the 32 chunk partials (coalesced rows of 272 floats).
    const float* base = ws + WS_PART + (size_t)ci * NCHUNK * PART_STRIDE;
    for (int e = tid; e < 272; e += 256) {
        float s = 0.0f;
#pragma unroll
        for (int ch = 0; ch < NCHUNK; ++ch)
            s += base[ch * PART_STRIDE + e];
        red2[e] = s;
    }
    __syncthreads();

    // sigma[r][c] = (P_rc - S_r*S_c/N) / (N-1)
    const float P_rc = red2[(r >> 2) * 68 + ((r & 3) << 4) + c];
    const float S_r  = red2[(r >> 2) * 68 + 64 + (r & 3)];
    const float S_c  = red2[(c >> 2) * 68 + 64 + (c & 3)];
    sig[r][c] = (P_rc - S_r * S_c * INV_N) * INV_NM1;
    __syncthreads();

    if (tid == 0) {
        float tr = 0.0f;
        for (int i = 0; i < 16; ++i) tr += sig[i][i];
        trace_s = tr;
    }
    __syncthreads();
    const float tr = trace_s;

    sig[r][c] = sig[r][c] / tr;                 // sigma_n
    p[r][c]   = (r == c) ? 1.0f : 0.0f;
    __syncthreads();

    for (int it = 0; it < 5; ++it) {
        float a = 0.0f;
        for (int k = 0; k < 16; ++k) a += p[r][k] * p[k][c];
        t1[r][c] = a;
        __syncthreads();
        float b2 = 0.0f;
        for (int k = 0; k < 16; ++k) b2 += t1[r][k] * p[k][c];
        t2[r][c] = b2;
        __syncthreads();
        float d = 0.0f;
        for (int k = 0; k < 16; ++k) d += t2[r][k] * sig[k][c];
        const float np = 0.5f * (3.0f * p[r][c] - d);
        __syncthreads();                        // all reads of p done
        p[r][c] = np;
        __syncthreads();
    }

    // Store W and the mean alongside (mean reconstructed in k_apply from S).
    ws[WS_W + ci * 256 + r * 16 + c] = p[r][c] / sqrtf(tr);
    if (tid < 16) {
        // stash S[a] (raw sum) right after all W blocks for k_apply
        ws[WS_W + CI * 256 + ci * 16 + tid] =
            red2[(tid >> 2) * 68 + 64 + (tid & 3)];
    }
}

// ---------------------------------------------------------------------------
// Kernel 3: out = ((x - m) @ W) * gamma + beta, folded as x @ (W*g) + c0.
// Grid: 32 ci * 64 chunks = 2048 blocks of 256 threads; quad owns a vector,
// lane (tid&3) produces output columns b0..b0+3 (W slab kept in registers).
// ---------------------------------------------------------------------------
__global__ __launch_bounds__(256) void k_apply(const float* __restrict__ x,
                                               const float* __restrict__ gamma,
                                               const float* __restrict__ beta,
                                               const float* __restrict__ ws,
                                               float* __restrict__ out) {
    const int ci    = blockIdx.x & 31;
    const int chunk = blockIdx.x >> 5;          // 0..63
    const int tid   = threadIdx.x;
    const int sub   = tid & 3;
    const int quad  = tid >> 2;
    const int b0    = sub * 4;

    const float* W = ws + WS_W + ci * 256;
    const float* S = ws + WS_W + CI * 256 + ci * 16;

    float g[4], c0[4];
#pragma unroll
    for (int i = 0; i < 4; ++i) g[i] = gamma[ci * 16 + b0 + i];

    float wg[16][4];
    float bias[4] = {0.0f, 0.0f, 0.0f, 0.0f};
#pragma unroll
    for (int a = 0; a < 16; ++a) {
        const float4 wr = *reinterpret_cast<const float4*>(W + a * 16 + b0);
        const float m = S[a] * INV_N;
        wg[a][0] = wr.x * g[0]; wg[a][1] = wr.y * g[1];
        wg[a][2] = wr.z * g[2]; wg[a][3] = wr.w * g[3];
        bias[0] += m * wr.x; bias[1] += m * wr.y;
        bias[2] += m * wr.z; bias[3] += m * wr.w;
    }
#pragma unroll
    for (int i = 0; i < 4; ++i)
        c0[i] = beta[ci * 16 + b0 + i] - bias[i] * g[i];

    const int n_base = chunk * 1024;            // 1024 vectors per block
    for (int it = 0; it < 16; ++it) {
        const int n  = n_base + it * 64 + quad;
        const int b  = n >> 5;
        const int co = n & 31;
        const size_t voff = ((size_t)(b * CI + ci) * CO + co) * A;
        const float* vptr = x + voff;

        float v[16];
#pragma unroll
        for (int j = 0; j < 4; ++j) {
            const float4 f = *reinterpret_cast<const float4*>(vptr + j * 4);
            v[4 * j + 0] = f.x; v[4 * j + 1] = f.y;
            v[4 * j + 2] = f.z; v[4 * j + 3] = f.w;
        }

        float acc[4] = {c0[0], c0[1], c0[2], c0[3]};
#pragma unroll
        for (int a = 0; a < 16; ++a) {
#pragma unroll
            for (int i = 0; i < 4; ++i) acc[i] += v[a] * wg[a][i];
        }

        float4 o;
        o.x = acc[0]; o.y = acc[1]; o.z = acc[2]; o.w = acc[3];
        *reinterpret_cast<float4*>(out + voff + b0) = o;
    }
}

// ---------------------------------------------------------------------------
extern "C" void kernel_launch(void* const* d_in, const int* in_sizes, int n_in,
                              void* d_out, int out_size, void* d_ws, size_t ws_size,
                              hipStream_t stream) {
    const float* x     = (const float*)d_in[0];
    const float* gamma = (const float*)d_in[1];
    const float* beta  = (const float*)d_in[2];
    float* out = (float*)d_out;
    float* ws  = (float*)d_ws;

    k_stats<<<dim3(1024), dim3(256), 0, stream>>>(x, ws);
    k_ns<<<dim3(32), dim3(256), 0, stream>>>(ws);
    k_apply<<<dim3(2048), dim3(256), 0, stream>>>(x, gamma, beta, ws, out);
}